// Round 7
// baseline (30.179 us; speedup 1.0000x reference)
//
#include <hip/hip_runtime.h>

#define NC 6
constexpr float HIER_W = 0.2f;

#define AS1 __attribute__((address_space(1)))
#define AS3 __attribute__((address_space(3)))

// Geometry (R5-proven): block = 256 thr = 4 waves. Each wave: NITER=8 iters x
// 128 rows, staged wave-private into LDS (no __syncthreads in the pipeline).
// Block covers 4*8*128 = 4096 rows -> grid = B/4096 = 1024 blocks.
#define NITER 8
#define STAGE_WORDS (128 * 6 + 128)   // 768 pred floats + 128 targets = 896 words (3584 B)

__global__ __launch_bounds__(256) void hloss_main(
    const float* __restrict__ preds,
    const int*   __restrict__ targets,
    const float* __restrict__ cw,
    const float* __restrict__ pen,
    float4* __restrict__ partial)
{
    __shared__ float s_cw[NC];
    __shared__ float s_pen[NC * NC];
    __shared__ float s_stage[4][2][STAGE_WORDS];   // [wave][buf][words]

    if (threadIdx.x < NC * NC) s_pen[threadIdx.x] = pen[threadIdx.x];
    if (threadIdx.x < NC)      s_cw[threadIdx.x]  = cw[threadIdx.x];
    __syncthreads();   // tables only; nothing else in flight yet

    const int wv   = threadIdx.x >> 6;
    const int lane = threadIdx.x & 63;
    const long long wrow0 = ((long long)blockIdx.x * 4 + wv) * (NITER * 128);

    float* const st0 = &s_stage[wv][0][0];
    float* const st1 = &s_stage[wv][1][0];

    // Stage 128 rows into wave-private buf: 3x16B + 2x4B global_load_lds.
    auto STAGE = [&](float* buf, int it) {
        const long long r0 = wrow0 + (long long)it * 128;
        const float* gp = preds + r0 * NC;            // 768 floats
        #pragma unroll
        for (int k = 0; k < 3; ++k) {
            __builtin_amdgcn_global_load_lds(
                (const AS1 void*)(gp + k * 256 + lane * 4),
                (AS3 void*)(buf + k * 256), 16, 0, 0);
        }
        const int* gt = targets + r0;                 // 128 ints
        #pragma unroll
        for (int k = 0; k < 2; ++k) {
            __builtin_amdgcn_global_load_lds(
                (const AS1 void*)(gt + k * 64 + lane),
                (AS3 void*)(buf + 768 + k * 64), 4, 0, 0);
        }
    };

    float a_num = 0.f, a_den = 0.f, a_h = 0.f;

    auto ROW = [&](const float* buf, int rr) {
        const int tr = __float_as_int(buf[768 + rr]);   // raw bits, no FP op
        float xr[NC], e[NC], s = 0.f;
        #pragma unroll
        for (int j = 0; j < NC; ++j) xr[j] = buf[rr * 6 + j];
        #pragma unroll
        for (int j = 0; j < NC; ++j) { e[j] = __expf(xr[j]); s += e[j]; }
        const float inv = __frcp_rn(s);

        float xt = xr[0];                                // compile-time-j select chain
        #pragma unroll
        for (int j = 1; j < NC; ++j) xt = (tr == j) ? xr[j] : xt;

        const float w = s_cw[tr];
        a_num += w * (__logf(s) - xt);
        a_den += w;

        const float* pr = s_pen + tr * NC;               // diag(pen)==1 trick
        float dot = 0.f;
        #pragma unroll
        for (int j = 0; j < NC; ++j) dot += e[j] * pr[j];
        a_h += (dot - __expf(xt)) * inv;
    };

    STAGE(st0, 0);
    STAGE(st1, 1);

    #pragma unroll
    for (int it = 0; it < NITER; ++it) {
        float* buf = (it & 1) ? st1 : st0;
        // counted wait: leave next stage's 5 loads in flight (T4); drain only at end
        if (it < NITER - 1) { asm volatile("s_waitcnt vmcnt(5)" ::: "memory"); }
        else                { asm volatile("s_waitcnt vmcnt(0)" ::: "memory"); }
        __builtin_amdgcn_sched_barrier(0);

        ROW(buf, lane);
        ROW(buf, 64 + lane);

        if (it + 2 < NITER) {
            // ensure this buf's ds_reads retired before overwriting (WAR)
            asm volatile("s_waitcnt lgkmcnt(0)" ::: "memory");
            __builtin_amdgcn_sched_barrier(0);
            STAGE(buf, it + 2);
        }
    }

    // wave butterfly reduction
    #pragma unroll
    for (int off = 32; off > 0; off >>= 1) {
        a_num += __shfl_xor(a_num, off);
        a_den += __shfl_xor(a_den, off);
        a_h   += __shfl_xor(a_h,   off);
    }

    __shared__ float red[3][4];
    if (lane == 0) { red[0][wv] = a_num; red[1][wv] = a_den; red[2][wv] = a_h; }
    __syncthreads();
    if (threadIdx.x == 0) {
        float n = 0.f, d = 0.f, h = 0.f;
        #pragma unroll
        for (int i = 0; i < 4; ++i) { n += red[0][i]; d += red[1][i]; h += red[2][i]; }
        partial[blockIdx.x] = make_float4(n, d, h, 0.f);
    }
}

// Single-wave tail: 1024 float4 = 16/lane; no LDS, no __syncthreads.
__global__ __launch_bounds__(64) void hloss_reduce(
    const float4* __restrict__ partial, int nblocks,
    float* __restrict__ out, float invB)
{
    float n = 0.f, d = 0.f, h = 0.f;
    for (int i = threadIdx.x; i < nblocks; i += 64) {
        float4 p = partial[i];
        n += p.x; d += p.y; h += p.z;
    }
    #pragma unroll
    for (int off = 32; off > 0; off >>= 1) {
        n += __shfl_xor(n, off);
        d += __shfl_xor(d, off);
        h += __shfl_xor(h, off);
    }
    if (threadIdx.x == 0) {
        const float ce = n / d;
        const float hh = h * invB;
        out[0] = ce + HIER_W * hh;  // total_loss
        out[1] = ce;                // ce_loss
        out[2] = hh;                // hierarchy_loss
    }
}

extern "C" void kernel_launch(void* const* d_in, const int* in_sizes, int n_in,
                              void* d_out, int out_size, void* d_ws, size_t ws_size,
                              hipStream_t stream)
{
    const float* preds   = (const float*)d_in[0];
    const int*   targets = (const int*)  d_in[1];
    const float* cw      = (const float*)d_in[2];
    const float* pen     = (const float*)d_in[3];
    float4* partial = (float4*)d_ws;
    float* out = (float*)d_out;

    const int B = in_sizes[1];           // 4,194,304 rows
    const int blocks = B / 4096;         // 1024, exact

    hipLaunchKernelGGL(hloss_main, dim3(blocks), dim3(256), 0, stream,
                       preds, targets, cw, pen, partial);
    hipLaunchKernelGGL(hloss_reduce, dim3(1), dim3(64), 0, stream,
                       partial, blocks, out, 1.0f / (float)B);
}

// Round 8
// 26.450 us; speedup vs baseline: 1.1410x; 1.1410x over previous
//
#include <hip/hip_runtime.h>

#define NC 6
constexpr float HIER_W = 0.2f;

#define AS1 __attribute__((address_space(1)))
#define AS3 __attribute__((address_space(3)))

// Geometry (R5-proven): block = 256 thr = 4 waves. Each wave: NITER=8 iters x
// 128 rows, staged wave-private into LDS (no __syncthreads in the pipeline).
// Block covers 4*8*128 = 4096 rows -> grid = B/4096 = 1024 blocks.
#define NITER 8
#define STAGE_WORDS (128 * 6 + 128)   // 768 pred floats + 128 targets = 896 words (3584 B)

__global__ __launch_bounds__(256) void hloss_main(
    const float* __restrict__ preds,
    const int*   __restrict__ targets,
    const float* __restrict__ cw,
    const float* __restrict__ pen,
    float4* __restrict__ partial)
{
    __shared__ float s_cw[NC];
    __shared__ float s_pen[NC * NC];
    __shared__ float s_stage[4][2][STAGE_WORDS];   // [wave][buf][words]

    if (threadIdx.x < NC * NC) s_pen[threadIdx.x] = pen[threadIdx.x];
    if (threadIdx.x < NC)      s_cw[threadIdx.x]  = cw[threadIdx.x];
    __syncthreads();   // tables only; nothing else in flight yet

    const int wv   = threadIdx.x >> 6;
    const int lane = threadIdx.x & 63;
    const long long wrow0 = ((long long)blockIdx.x * 4 + wv) * (NITER * 128);

    float* const st0 = &s_stage[wv][0][0];
    float* const st1 = &s_stage[wv][1][0];

    // Stage 128 rows into wave-private buf: 3x16B + 2x4B global_load_lds.
    auto STAGE = [&](float* buf, int it) {
        const long long r0 = wrow0 + (long long)it * 128;
        const float* gp = preds + r0 * NC;            // 768 floats
        #pragma unroll
        for (int k = 0; k < 3; ++k) {
            __builtin_amdgcn_global_load_lds(
                (const AS1 void*)(gp + k * 256 + lane * 4),
                (AS3 void*)(buf + k * 256), 16, 0, 0);
        }
        const int* gt = targets + r0;                 // 128 ints
        #pragma unroll
        for (int k = 0; k < 2; ++k) {
            __builtin_amdgcn_global_load_lds(
                (const AS1 void*)(gt + k * 64 + lane),
                (AS3 void*)(buf + 768 + k * 64), 4, 0, 0);
        }
    };

    float a_num = 0.f, a_den = 0.f, a_h = 0.f;

    auto ROW = [&](const float* buf, int rr) {
        const int tr = __float_as_int(buf[768 + rr]);   // raw bits, no FP op
        float xr[NC], e[NC], s = 0.f;
        #pragma unroll
        for (int j = 0; j < NC; ++j) xr[j] = buf[rr * 6 + j];
        #pragma unroll
        for (int j = 0; j < NC; ++j) { e[j] = __expf(xr[j]); s += e[j]; }
        const float inv = __frcp_rn(s);

        float xt = xr[0];                                // compile-time-j select chain
        #pragma unroll
        for (int j = 1; j < NC; ++j) xt = (tr == j) ? xr[j] : xt;

        const float w = s_cw[tr];
        a_num += w * (__logf(s) - xt);
        a_den += w;

        const float* pr = s_pen + tr * NC;               // diag(pen)==1 trick
        float dot = 0.f;
        #pragma unroll
        for (int j = 0; j < NC; ++j) dot += e[j] * pr[j];
        a_h += (dot - __expf(xt)) * inv;
    };

    STAGE(st0, 0);
    STAGE(st1, 1);

    #pragma unroll
    for (int it = 0; it < NITER; ++it) {
        float* buf = (it & 1) ? st1 : st0;
        // counted wait: leave next stage's 5 loads in flight (T4); drain only at end
        if (it < NITER - 1) { asm volatile("s_waitcnt vmcnt(5)" ::: "memory"); }
        else                { asm volatile("s_waitcnt vmcnt(0)" ::: "memory"); }
        __builtin_amdgcn_sched_barrier(0);

        ROW(buf, lane);
        ROW(buf, 64 + lane);

        if (it + 2 < NITER) {
            // ensure this buf's ds_reads retired before overwriting (WAR)
            asm volatile("s_waitcnt lgkmcnt(0)" ::: "memory");
            __builtin_amdgcn_sched_barrier(0);
            STAGE(buf, it + 2);
        }
    }

    // wave butterfly reduction
    #pragma unroll
    for (int off = 32; off > 0; off >>= 1) {
        a_num += __shfl_xor(a_num, off);
        a_den += __shfl_xor(a_den, off);
        a_h   += __shfl_xor(a_h,   off);
    }

    __shared__ float red[3][4];
    if (lane == 0) { red[0][wv] = a_num; red[1][wv] = a_den; red[2][wv] = a_h; }
    __syncthreads();
    if (threadIdx.x == 0) {
        float n = 0.f, d = 0.f, h = 0.f;
        #pragma unroll
        for (int i = 0; i < 4; ++i) { n += red[0][i]; d += red[1][i]; h += red[2][i]; }
        partial[blockIdx.x] = make_float4(n, d, h, 0.f);
    }
}

// 256-thread tail over exactly 1024 partials: 4 INDEPENDENT float4 loads per
// thread (one latency), butterfly, tiny LDS combine.
__global__ __launch_bounds__(256) void hloss_reduce(
    const float4* __restrict__ partial,
    float* __restrict__ out, float invB)
{
    const int t = threadIdx.x;
    float4 p0 = partial[t];
    float4 p1 = partial[t + 256];
    float4 p2 = partial[t + 512];
    float4 p3 = partial[t + 768];

    float n = p0.x + p1.x + p2.x + p3.x;
    float d = p0.y + p1.y + p2.y + p3.y;
    float h = p0.z + p1.z + p2.z + p3.z;

    #pragma unroll
    for (int off = 32; off > 0; off >>= 1) {
        n += __shfl_xor(n, off);
        d += __shfl_xor(d, off);
        h += __shfl_xor(h, off);
    }
    __shared__ float red[3][4];
    const int wave = t >> 6;
    const int lane = t & 63;
    if (lane == 0) { red[0][wave] = n; red[1][wave] = d; red[2][wave] = h; }
    __syncthreads();
    if (t == 0) {
        float N = 0.f, D = 0.f, H = 0.f;
        #pragma unroll
        for (int i = 0; i < 4; ++i) { N += red[0][i]; D += red[1][i]; H += red[2][i]; }
        const float ce = N / D;
        const float hh = H * invB;
        out[0] = ce + HIER_W * hh;  // total_loss
        out[1] = ce;                // ce_loss
        out[2] = hh;                // hierarchy_loss
    }
}

extern "C" void kernel_launch(void* const* d_in, const int* in_sizes, int n_in,
                              void* d_out, int out_size, void* d_ws, size_t ws_size,
                              hipStream_t stream)
{
    const float* preds   = (const float*)d_in[0];
    const int*   targets = (const int*)  d_in[1];
    const float* cw      = (const float*)d_in[2];
    const float* pen     = (const float*)d_in[3];
    float4* partial = (float4*)d_ws;
    float* out = (float*)d_out;

    const int B = in_sizes[1];           // 4,194,304 rows
    const int blocks = B / 4096;         // 1024, exact

    hipLaunchKernelGGL(hloss_main, dim3(blocks), dim3(256), 0, stream,
                       preds, targets, cw, pen, partial);
    hipLaunchKernelGGL(hloss_reduce, dim3(1), dim3(256), 0, stream,
                       partial, out, 1.0f / (float)B);
}

// Round 9
// 26.350 us; speedup vs baseline: 1.1453x; 1.0038x over previous
//
#include <hip/hip_runtime.h>

#define NC 6
constexpr float HIER_W = 0.2f;

#define AS1 __attribute__((address_space(1)))
#define AS3 __attribute__((address_space(3)))

// Depth-4 wave-private pipeline. Block = 256 thr = 4 waves.
// Each wave: NITER=16 iters x 64 rows; 4 buffers of 1792 B in flight.
// Block covers 4*16*64 = 4096 rows -> grid = B/4096 = 1024 blocks.
// LDS = 4 waves * 4 bufs * 448 words * 4B = 28.7 KB -> 5 blocks/CU (as R5/R8).
#define NITER 16
#define NBUF 4
#define BUF_WORDS (64 * 6 + 64)   // 384 pred floats + 64 targets = 448 words (1792 B)

__global__ __launch_bounds__(256) void hloss_main(
    const float* __restrict__ preds,
    const int*   __restrict__ targets,
    const float* __restrict__ cw,
    const float* __restrict__ pen,
    float4* __restrict__ partial)
{
    __shared__ float s_cw[NC];
    __shared__ float s_pen[NC * NC];
    __shared__ float s_stage[4][NBUF][BUF_WORDS];   // [wave][buf][words]

    if (threadIdx.x < NC * NC) s_pen[threadIdx.x] = pen[threadIdx.x];
    if (threadIdx.x < NC)      s_cw[threadIdx.x]  = cw[threadIdx.x];
    __syncthreads();   // tables only; nothing else in flight yet

    const int wv   = threadIdx.x >> 6;
    const int lane = threadIdx.x & 63;
    const long long wrow0 = ((long long)blockIdx.x * 4 + wv) * (NITER * 64);

    // Stage 64 rows into wave-private buf: 1x16B + 2x4B (preds) + 1x4B (targets).
    auto STAGE = [&](int bi, int it) {
        float* buf = &s_stage[wv][bi][0];
        const long long r0 = wrow0 + (long long)it * 64;
        const float* gp = preds + r0 * NC;            // 384 floats = 1536 B
        __builtin_amdgcn_global_load_lds(
            (const AS1 void*)(gp + lane * 4),  (AS3 void*)(buf),       16, 0, 0);
        __builtin_amdgcn_global_load_lds(
            (const AS1 void*)(gp + 256 + lane), (AS3 void*)(buf + 256),  4, 0, 0);
        __builtin_amdgcn_global_load_lds(
            (const AS1 void*)(gp + 320 + lane), (AS3 void*)(buf + 320),  4, 0, 0);
        const int* gt = targets + r0;                 // 64 ints = 256 B
        __builtin_amdgcn_global_load_lds(
            (const AS1 void*)(gt + lane),       (AS3 void*)(buf + 384),  4, 0, 0);
    };

    float a_num = 0.f, a_den = 0.f, a_h = 0.f;

    auto ROW = [&](const float* buf) {
        const int tr = __float_as_int(buf[384 + lane]);  // raw bits, no FP op
        float xr[NC], e[NC], s = 0.f;
        #pragma unroll
        for (int j = 0; j < NC; ++j) xr[j] = buf[lane * 6 + j];
        #pragma unroll
        for (int j = 0; j < NC; ++j) { e[j] = __expf(xr[j]); s += e[j]; }
        const float inv = __frcp_rn(s);

        float xt = xr[0];                                // compile-time-j select chain
        #pragma unroll
        for (int j = 1; j < NC; ++j) xt = (tr == j) ? xr[j] : xt;

        const float w = s_cw[tr];
        a_num += w * (__logf(s) - xt);
        a_den += w;

        const float* pr = s_pen + tr * NC;               // diag(pen)==1 trick
        float dot = 0.f;
        #pragma unroll
        for (int j = 0; j < NC; ++j) dot += e[j] * pr[j];
        a_h += (dot - __expf(xt)) * inv;
    };

    // Prologue: fill all 4 buffers (16 loads outstanding).
    STAGE(0, 0); STAGE(1, 1); STAGE(2, 2); STAGE(3, 3);

    #pragma unroll
    for (int it = 0; it < NITER; ++it) {
        // counted wait: current buffer landed; newer buffers' loads stay in
        // flight (4 loads each). rem = min(3, NITER-1-it) buffers ahead.
        const int rem = (NITER - 1 - it) < 3 ? (NITER - 1 - it) : 3;
        switch (rem) {   // it is compile-time after unroll -> one case survives
            case 3: asm volatile("s_waitcnt vmcnt(12)" ::: "memory"); break;
            case 2: asm volatile("s_waitcnt vmcnt(8)"  ::: "memory"); break;
            case 1: asm volatile("s_waitcnt vmcnt(4)"  ::: "memory"); break;
            default: asm volatile("s_waitcnt vmcnt(0)" ::: "memory"); break;
        }
        __builtin_amdgcn_sched_barrier(0);

        ROW(&s_stage[wv][it & (NBUF - 1)][0]);

        if (it + NBUF < NITER) {
            // this buf's ds_reads must retire before overwrite (WAR)
            asm volatile("s_waitcnt lgkmcnt(0)" ::: "memory");
            __builtin_amdgcn_sched_barrier(0);
            STAGE(it & (NBUF - 1), it + NBUF);
        }
    }

    // wave butterfly reduction
    #pragma unroll
    for (int off = 32; off > 0; off >>= 1) {
        a_num += __shfl_xor(a_num, off);
        a_den += __shfl_xor(a_den, off);
        a_h   += __shfl_xor(a_h,   off);
    }

    __shared__ float red[3][4];
    if (lane == 0) { red[0][wv] = a_num; red[1][wv] = a_den; red[2][wv] = a_h; }
    __syncthreads();
    if (threadIdx.x == 0) {
        float n = 0.f, d = 0.f, h = 0.f;
        #pragma unroll
        for (int i = 0; i < 4; ++i) { n += red[0][i]; d += red[1][i]; h += red[2][i]; }
        partial[blockIdx.x] = make_float4(n, d, h, 0.f);
    }
}

// 256-thread tail over exactly 1024 partials: 4 INDEPENDENT float4 loads per
// thread (one latency), butterfly, tiny LDS combine.  (R8-proven)
__global__ __launch_bounds__(256) void hloss_reduce(
    const float4* __restrict__ partial,
    float* __restrict__ out, float invB)
{
    const int t = threadIdx.x;
    float4 p0 = partial[t];
    float4 p1 = partial[t + 256];
    float4 p2 = partial[t + 512];
    float4 p3 = partial[t + 768];

    float n = p0.x + p1.x + p2.x + p3.x;
    float d = p0.y + p1.y + p2.y + p3.y;
    float h = p0.z + p1.z + p2.z + p3.z;

    #pragma unroll
    for (int off = 32; off > 0; off >>= 1) {
        n += __shfl_xor(n, off);
        d += __shfl_xor(d, off);
        h += __shfl_xor(h, off);
    }
    __shared__ float red[3][4];
    const int wave = t >> 6;
    const int lane = t & 63;
    if (lane == 0) { red[0][wave] = n; red[1][wave] = d; red[2][wave] = h; }
    __syncthreads();
    if (t == 0) {
        float N = 0.f, D = 0.f, H = 0.f;
        #pragma unroll
        for (int i = 0; i < 4; ++i) { N += red[0][i]; D += red[1][i]; H += red[2][i]; }
        const float ce = N / D;
        const float hh = H * invB;
        out[0] = ce + HIER_W * hh;  // total_loss
        out[1] = ce;                // ce_loss
        out[2] = hh;                // hierarchy_loss
    }
}

extern "C" void kernel_launch(void* const* d_in, const int* in_sizes, int n_in,
                              void* d_out, int out_size, void* d_ws, size_t ws_size,
                              hipStream_t stream)
{
    const float* preds   = (const float*)d_in[0];
    const int*   targets = (const int*)  d_in[1];
    const float* cw      = (const float*)d_in[2];
    const float* pen     = (const float*)d_in[3];
    float4* partial = (float4*)d_ws;
    float* out = (float*)d_out;

    const int B = in_sizes[1];           // 4,194,304 rows
    const int blocks = B / 4096;         // 1024, exact

    hipLaunchKernelGGL(hloss_main, dim3(blocks), dim3(256), 0, stream,
                       preds, targets, cw, pen, partial);
    hipLaunchKernelGGL(hloss_reduce, dim3(1), dim3(256), 0, stream,
                       partial, out, 1.0f / (float)B);
}